// Round 3
// baseline (181.701 us; speedup 1.0000x reference)
//
#include <hip/hip_runtime.h>

#define NN 50000
#define NE 800000
#define DD 128
#define TILE_M 64
#define CAP 64            // per-node slot capacity; deg ~ Poisson(16), P(>64) ~ 1e-20

#define NBG ((NN + TILE_M - 1) / TILE_M)   // 782 gemm blocks
#define NBS ((NE + 255) / 256)             // 3125 scatter blocks, 1 edge/thread

typedef __attribute__((ext_vector_type(8))) short short8;
typedef __attribute__((ext_vector_type(4))) float f32x4;

__device__ __forceinline__ unsigned short f2bf(float f) {
    unsigned int u = __float_as_uint(f);
    u += 0x7fffu + ((u >> 16) & 1u);   // RNE
    return (unsigned short)(u >> 16);
}

// ---------------- prologue: zero deg + W fp32->bf16 (replaces memset) --------
__global__ __launch_bounds__(256) void prologue(
    const float* __restrict__ W, unsigned short* __restrict__ Wbf,
    int* __restrict__ deg)
{
    const int t = blockIdx.x * 256 + threadIdx.x;
    for (int i = t; i < NN; i += 64 * 256) deg[i] = 0;
    if (blockIdx.x == 0) {
        for (int i = threadIdx.x; i < 128 * 32; i += 256) {
            const float4 w4 = ((const float4*)W)[i];
            ushort4 s4;
            s4.x = f2bf(w4.x); s4.y = f2bf(w4.y);
            s4.z = f2bf(w4.z); s4.w = f2bf(w4.w);
            *(ushort4*)(Wbf + i * 4) = s4;
        }
    }
}

// ---------------- scatter: CSR-ish build, 1 thread = 1 edge ------------------
// R1/R2 proved atomic placement (node-residue, line-residue) is irrelevant:
// device-scope atomics resolve at an address-interleaved home regardless of
// issuing XCD. So: no replication, no partition filter. Each edge read once
// (rows 3.2 MB + cols 3.2 MB, was 25.6+3.2), 800K atomics, 800K 4B slot
// writes. Separate dispatch so rocprof prices this phase alone.
__global__ __launch_bounds__(256) void scatter_kernel(
    const int* __restrict__ ei, int* __restrict__ deg, int* __restrict__ slots)
{
    const int e = blockIdx.x * 256 + threadIdx.x;
    if (e < NE) {
        const int r = ei[e];
        const int c = ei[NE + e];
        const int p = atomicAdd(&deg[r], 1);
        if (p < CAP) slots[r * CAP + p] = c;
    }
}

// ---------------- GEMM: h = x@W^T + b -> out (fp32) and hbf (bf16) ----------
// ZERO LDS: A-fragments per-lane from x (each element exactly once per block,
// fp32->bf16 in reg); B-fragments short8 from bf16 W in workspace (32 KB,
// L2-resident).
__global__ __launch_bounds__(256, 6) void gemm_kernel(
    const float* __restrict__ x, const unsigned short* __restrict__ Wbf,
    const float* __restrict__ b, float* __restrict__ out,
    unsigned short* __restrict__ hbf)
{
    const int t    = threadIdx.x;
    const int lane = t & 63;
    const int wave = t >> 6;
    const int m16  = lane & 15;
    const int quad = lane >> 4;

    const int row0 = blockIdx.x * TILE_M;
    int gr = row0 + wave * 16 + m16;
    if (gr > NN - 1) gr = NN - 1;          // clamped rows never stored

    short8 afrag[4];
#pragma unroll
    for (int kc = 0; kc < 4; ++kc) {
        const float4 a0 = *(const float4*)(x + (size_t)gr * 128 + kc * 32 + quad * 8);
        const float4 a1 = *(const float4*)(x + (size_t)gr * 128 + kc * 32 + quad * 8 + 4);
        short8 af;
        af[0] = (short)f2bf(a0.x); af[1] = (short)f2bf(a0.y);
        af[2] = (short)f2bf(a0.z); af[3] = (short)f2bf(a0.w);
        af[4] = (short)f2bf(a1.x); af[5] = (short)f2bf(a1.y);
        af[6] = (short)f2bf(a1.z); af[7] = (short)f2bf(a1.w);
        afrag[kc] = af;
    }

    f32x4 acc[8];
#pragma unroll
    for (int nt = 0; nt < 8; ++nt) acc[nt] = (f32x4){0.f, 0.f, 0.f, 0.f};

#pragma unroll
    for (int kc = 0; kc < 4; ++kc) {
#pragma unroll
        for (int nt = 0; nt < 8; ++nt) {
            const short8 bfrag =
                *(const short8*)(Wbf + (nt * 16 + m16) * 128 + kc * 32 + quad * 8);
            acc[nt] = __builtin_amdgcn_mfma_f32_16x16x32_bf16(
                afrag[kc], bfrag, acc[nt], 0, 0, 0);
        }
    }

    const int rbase = row0 + wave * 16 + quad * 4;
#pragma unroll
    for (int nt = 0; nt < 8; ++nt) {
        const float bias = b[nt * 16 + m16];
#pragma unroll
        for (int r = 0; r < 4; ++r) {
            const int grow = rbase + r;
            if (grow < NN) {
                const float v = acc[nt][r] + bias;
                out[(size_t)grow * 128 + nt * 16 + m16] = v;   // residual base
                hbf[(size_t)grow * 128 + nt * 16 + m16] = f2bf(v);
            }
        }
    }
}

// ---------------- agg: out[n] += sum_{k<deg[n]} h[slots[n][k]] ------------
// One wave per node. Lane = (g,s): g=lane>>4 picks one of 4 concurrent
// edges, s=lane&15 owns 8 cols (16 B uint4 gather). 16 edges/round, 4
// exec-masked loads in flight. Cross-group reduce: 2 shfl_xor steps.
__global__ __launch_bounds__(256) void agg_kernel(
    const int* __restrict__ deg, const int* __restrict__ slots,
    const unsigned short* __restrict__ hbf, float* __restrict__ out)
{
    const int n = (blockIdx.x * 256 + threadIdx.x) >> 6;   // wave-uniform
    if (n >= NN) return;
    const int lane = threadIdx.x & 63;
    const int g = lane >> 4;       // edge group 0..3
    const int s = lane & 15;       // col sub-lane: cols s*8 .. s*8+7

    const int dn_raw = deg[n];
    const int dn = min(dn_raw, CAP);
    // exec-masked: skip unused slot lines (deg ~16 -> typically 1 of 4 lines)
    const int idx = (lane < dn) ? slots[n * CAP + lane] : 0;
    float4 r0, r1;
    if (g == 0) {
        r0 = *(const float4*)(out + (size_t)n * 128 + s * 8);
        r1 = *(const float4*)(out + (size_t)n * 128 + s * 8 + 4);
    }

    float acc[8];
#pragma unroll
    for (int i = 0; i < 8; ++i) acc[i] = 0.f;

    for (int k = 0; k < dn; k += 16) {
        uint4 p[4];
#pragma unroll
        for (int bb = 0; bb < 4; ++bb) {
            const int e = k + bb * 4 + g;
            const int c = __shfl(idx, e, 64);
            p[bb] = (uint4){0u, 0u, 0u, 0u};
            if (e < dn)
                p[bb] = *(const uint4*)(hbf + (size_t)c * 128 + s * 8);
        }
#pragma unroll
        for (int bb = 0; bb < 4; ++bb) {
            acc[0] += __uint_as_float(p[bb].x << 16);
            acc[1] += __uint_as_float(p[bb].x & 0xffff0000u);
            acc[2] += __uint_as_float(p[bb].y << 16);
            acc[3] += __uint_as_float(p[bb].y & 0xffff0000u);
            acc[4] += __uint_as_float(p[bb].z << 16);
            acc[5] += __uint_as_float(p[bb].z & 0xffff0000u);
            acc[6] += __uint_as_float(p[bb].w << 16);
            acc[7] += __uint_as_float(p[bb].w & 0xffff0000u);
        }
    }

#pragma unroll
    for (int i = 0; i < 8; ++i) acc[i] += __shfl_xor(acc[i], 16, 64);
#pragma unroll
    for (int i = 0; i < 8; ++i) acc[i] += __shfl_xor(acc[i], 32, 64);

    if (g == 0) {
        r0.x += acc[0]; r0.y += acc[1]; r0.z += acc[2]; r0.w += acc[3];
        r1.x += acc[4]; r1.y += acc[5]; r1.z += acc[6]; r1.w += acc[7];
        *(float4*)(out + (size_t)n * 128 + s * 8)     = r0;
        *(float4*)(out + (size_t)n * 128 + s * 8 + 4) = r1;
    }
}

extern "C" void kernel_launch(void* const* d_in, const int* in_sizes, int n_in,
                              void* d_out, int out_size, void* d_ws, size_t ws_size,
                              hipStream_t stream)
{
    const float* x  = (const float*)d_in[0];
    const int*   ei = (const int*)d_in[1];   // int32
    const float* W  = (const float*)d_in[2];
    const float* b  = (const float*)d_in[3];
    float* out = (float*)d_out;

    // Workspace (~25.9 MB): hbf | slots | deg | Wbf
    unsigned short* hbf   = (unsigned short*)d_ws;                // NN*DD bf16
    int*            slots = (int*)(hbf + (size_t)NN * DD);        // NN*CAP
    int*            deg   = slots + (size_t)NN * CAP;             // NN
    unsigned short* Wbf   = (unsigned short*)(deg + NN);          // 128*128 bf16

    prologue<<<64, 256, 0, stream>>>(W, Wbf, deg);

    scatter_kernel<<<NBS, 256, 0, stream>>>(ei, deg, slots);

    gemm_kernel<<<NBG, 256, 0, stream>>>(x, Wbf, b, out, hbf);

    agg_kernel<<<(NN * 64 + 255) / 256, 256, 0, stream>>>(deg, slots, hbf, out);
}